// Round 18
// baseline (1069.986 us; speedup 1.0000x reference)
//
#include <hip/hip_runtime.h>
#include <hip/hip_bf16.h>

// ---------------------------------------------------------------------------
// GraphActorNetwork: movement MLP (16->128->128->128) -> scatter-mean over
// edges -> phase MLP (128->128->128->1).
// Round 18: serial-glue squeeze on r17 (285us). (1) scan_sum folded into
// hist: the hist role also bumps bsum[d>>10] (1M extra int atomics over 123
// counters, hidden under movA) -> scan_sum dispatch deleted. (2) histB/
// fillB 512 -> 256: same atomic work, half the co-resident pollution of mov
// (the 1024->512 step bought 12us in r17). (3) prep zeroes bsum too.
// DAG: prep -> [movA||hist+bsum] -> scan_fill -> [movB||fill] -> phase_fused.
// mov body (r10 config), phase_fused, scan_fill unchanged. absmax 2.9e-3.
// ---------------------------------------------------------------------------

typedef __attribute__((ext_vector_type(8))) short short8;
typedef __attribute__((ext_vector_type(4))) float f32x4;

union U8 { short8 s8; unsigned int u[4]; };

__device__ __forceinline__ float bf2f(unsigned short u) {
  return __uint_as_float(((unsigned int)u) << 16);
}
__device__ __forceinline__ unsigned short f2bf(float f) {
  unsigned int u = __float_as_uint(f);
  u = (u + 0x7fffu + ((u >> 16) & 1u)) >> 16;   // RNE
  return (unsigned short)u;
}
__device__ __forceinline__ unsigned int pk2(float a, float b) {
  __hip_bfloat162 h = __float22bfloat162_rn(make_float2(a, b));
  unsigned int u;
  __builtin_memcpy(&u, &h, 4);
  return u;
}

// ---------------- prep: bf16 transposed weights + zero cnt/bsum -------------
__global__ __launch_bounds__(256)
void prep_weights(const float* __restrict__ W1, const float* __restrict__ W2,
                  const float* __restrict__ W3, const float* __restrict__ W4,
                  const float* __restrict__ W5,
                  unsigned short* __restrict__ w1t, unsigned short* __restrict__ w2t,
                  unsigned short* __restrict__ w3t, unsigned short* __restrict__ w4t,
                  unsigned short* __restrict__ w5t,
                  int* __restrict__ cnt, int nph, int* __restrict__ bsum, int nb) {
  int t = blockIdx.x * blockDim.x + threadIdx.x;
  int stride = gridDim.x * blockDim.x;
  if (t < 128 * 32) {
    int c = t >> 5, k = t & 31;
    w1t[t] = (k < 16) ? f2bf(W1[k * 128 + c]) : 0;
  }
  for (int i = t; i < 128 * 128; i += stride) {
    int c = i >> 7, k = i & 127;
    w2t[i] = f2bf(W2[k * 128 + c]);
    w3t[i] = f2bf(W3[k * 128 + c]);
    w4t[i] = f2bf(W4[k * 128 + c]);
    w5t[i] = f2bf(W5[k * 128 + c]);
  }
  for (int i = t; i < nph; i += stride) cnt[i] = 0;
  if (t < nb) bsum[t] = 0;
}

// ---------------- mov tile body (r10 proven) --------------------------------
__device__ __forceinline__
void mov_tile(int rowBlk, unsigned short* sH,
              const float* __restrict__ x,
              const unsigned short* __restrict__ w1t,
              const unsigned short* __restrict__ w2t,
              const unsigned short* __restrict__ w3t,
              const float* __restrict__ b1, const float* __restrict__ b2,
              const float* __restrict__ b3,
              unsigned short* __restrict__ hout, int nrows) {
  const int tid  = threadIdx.x;
  const int lane = tid & 63;
  const int w    = tid >> 6;
  const int li   = lane & 15;
  const int g    = lane >> 4;
  const int r0w  = (w & 1) * 32;
  const int c0   = (w >> 1) * 64;

  f32x4 acc[2][4];
  short8 Bf[4][4];

#pragma unroll
  for (int cf = 0; cf < 4; ++cf) {
    float4 b4 = *(const float4*)&b1[c0 + cf * 16 + g * 4];
#pragma unroll
    for (int rf = 0; rf < 2; ++rf) {
      acc[rf][cf][0] = b4.x; acc[rf][cf][1] = b4.y;
      acc[rf][cf][2] = b4.z; acc[rf][cf][3] = b4.w;
    }
  }
  {
    short8 Ax[2];
#pragma unroll
    for (int rf = 0; rf < 2; ++rf) {
      U8 a; a.s8 = (short8)0;
      int row = rowBlk + r0w + rf * 16 + li;
      if (g < 2 && row < nrows) {
        const float* xp = x + (size_t)row * 16 + g * 8;
        float4 u0 = *(const float4*)xp;
        float4 u1 = *(const float4*)(xp + 4);
        a.u[0] = pk2(u0.x, u0.y); a.u[1] = pk2(u0.z, u0.w);
        a.u[2] = pk2(u1.x, u1.y); a.u[3] = pk2(u1.z, u1.w);
      }
      Ax[rf] = a.s8;
    }
    short8 B1[4];
#pragma unroll
    for (int cf = 0; cf < 4; ++cf)
      B1[cf] = *(const short8*)&w1t[(c0 + cf * 16 + li) * 32 + g * 8];
#pragma unroll
    for (int rf = 0; rf < 2; ++rf)
#pragma unroll
      for (int cf = 0; cf < 4; ++cf)
        acc[rf][cf] = __builtin_amdgcn_mfma_f32_16x16x32_bf16(B1[cf], Ax[rf], acc[rf][cf], 0, 0, 0);
  }

#pragma unroll
  for (int rf = 0; rf < 2; ++rf) {
    int s = r0w + rf * 16 + li;
    unsigned short* dst = &sH[s * 128 + (g & 1) * 4];
    int sx = s & 7;
#pragma unroll
    for (int cf = 0; cf < 4; ++cf) {
      int gi = (c0 >> 3) + cf * 2 + (g >> 1);
      int slot = gi ^ sx;
      uint2 u;
      u.x = pk2(fmaxf(acc[rf][cf][0], 0.f), fmaxf(acc[rf][cf][1], 0.f));
      u.y = pk2(fmaxf(acc[rf][cf][2], 0.f), fmaxf(acc[rf][cf][3], 0.f));
      *(uint2*)(dst + slot * 8) = u;
    }
  }
  __syncthreads();

  const unsigned short* wts[2] = { w2t, w3t };
  const float* bs[2] = { b2, b3 };
#pragma unroll 1
  for (int layer = 0; layer < 2; ++layer) {
    const unsigned short* wt = wts[layer];
    const float* bb = bs[layer];
#pragma unroll
    for (int ks = 0; ks < 4; ++ks)
#pragma unroll
      for (int cf = 0; cf < 4; ++cf)
        Bf[ks][cf] = *(const short8*)&wt[(c0 + cf * 16 + li) * 128 + ks * 32 + g * 8];

#pragma unroll
    for (int cf = 0; cf < 4; ++cf) {
      float4 b4 = *(const float4*)&bb[c0 + cf * 16 + g * 4];
#pragma unroll
      for (int rf = 0; rf < 2; ++rf) {
        acc[rf][cf][0] = b4.x; acc[rf][cf][1] = b4.y;
        acc[rf][cf][2] = b4.z; acc[rf][cf][3] = b4.w;
      }
    }

#pragma unroll
    for (int ks = 0; ks < 4; ++ks) {
      short8 Ar[2];
#pragma unroll
      for (int rf = 0; rf < 2; ++rf) {
        int s = r0w + rf * 16 + li;
        int slot = (ks * 4 + g) ^ (s & 7);
        Ar[rf] = *(const short8*)&sH[s * 128 + slot * 8];
      }
#pragma unroll
      for (int rf = 0; rf < 2; ++rf)
#pragma unroll
        for (int cf = 0; cf < 4; ++cf)
          acc[rf][cf] = __builtin_amdgcn_mfma_f32_16x16x32_bf16(Bf[ks][cf], Ar[rf], acc[rf][cf], 0, 0, 0);
    }
    __syncthreads();

#pragma unroll
    for (int rf = 0; rf < 2; ++rf) {
      int s = r0w + rf * 16 + li;
      unsigned short* dst = &sH[s * 128 + (g & 1) * 4];
      int sx = s & 7;
#pragma unroll
      for (int cf = 0; cf < 4; ++cf) {
        int gi = (c0 >> 3) + cf * 2 + (g >> 1);
        int slot = gi ^ sx;
        uint2 u;
        u.x = pk2(fmaxf(acc[rf][cf][0], 0.f), fmaxf(acc[rf][cf][1], 0.f));
        u.y = pk2(fmaxf(acc[rf][cf][2], 0.f), fmaxf(acc[rf][cf][3], 0.f));
        *(uint2*)(dst + slot * 8) = u;
      }
    }
    __syncthreads();
  }

  {
    int r = tid >> 2;
    int q = tid & 3;
    int grow = rowBlk + r;
    if (grow < nrows) {
#pragma unroll
      for (int i = 0; i < 4; ++i) {
        int gi = q * 4 + i;
        int slot = gi ^ (r & 7);
        short8 v = *(const short8*)&sH[r * 128 + slot * 8];
        *(short8*)(hout + (size_t)grow * 128 + gi * 8) = v;
      }
    }
  }
}

// role map: every k-th block (b%k==k-1, b/k<otherB) takes the "other" role.
__device__ __forceinline__ bool role_other(int b, int k, int otherB, int* oIdx, int* mIdx) {
  bool other = ((b % k) == (k - 1)) && ((b / k) < otherB);
  *oIdx = b / k;
  int before = min((b + 1) / k, otherB);
  *mIdx = b - before;
  return other;
}

// ---------------- K1: movA interleaved with hist (+bsum) --------------------
__global__ __launch_bounds__(256)
void mov_hist_kernel(const float* __restrict__ x,
                     const unsigned short* __restrict__ w1t,
                     const unsigned short* __restrict__ w2t,
                     const unsigned short* __restrict__ w3t,
                     const float* __restrict__ b1, const float* __restrict__ b2,
                     const float* __restrict__ b3,
                     unsigned short* __restrict__ hout, int nrows,
                     const int* __restrict__ edst, int* __restrict__ cnt,
                     int* __restrict__ bsum, int ne, int k, int histB) {
  __shared__ unsigned short sH[64 * 128];
  int oIdx, mIdx;
  if (role_other(blockIdx.x, k, histB, &oIdx, &mIdx)) {
    int i = oIdx * 256 + threadIdx.x;
    int stride = histB * 256;
    for (int e = i; e < ne; e += stride) {
      int d = edst[e];
      atomicAdd(cnt + d, 1);
      atomicAdd(bsum + (d >> 10), 1);
    }
    return;
  }
  mov_tile(mIdx * 64, sH, x, w1t, w2t, w3t, b1, b2, b3, hout, nrows);
}

// ---------------- K2: movB interleaved with fill ----------------------------
__global__ __launch_bounds__(256)
void mov_fill_kernel(const float* __restrict__ x,
                     const unsigned short* __restrict__ w1t,
                     const unsigned short* __restrict__ w2t,
                     const unsigned short* __restrict__ w3t,
                     const float* __restrict__ b1, const float* __restrict__ b2,
                     const float* __restrict__ b3,
                     unsigned short* __restrict__ hout, int nrows, int movABlocks,
                     const int* __restrict__ esrc, const int* __restrict__ edst,
                     int* __restrict__ cursor, int* __restrict__ csr, int ne,
                     int k, int fillB) {
  __shared__ unsigned short sH[64 * 128];
  int oIdx, mIdx;
  if (role_other(blockIdx.x, k, fillB, &oIdx, &mIdx)) {
    int i = oIdx * 256 + threadIdx.x;
    int stride = fillB * 256;
    for (int e = i; e < ne; e += stride) {
      int d = edst[e];
      int pos = atomicAdd(cursor + d, 1);
      csr[pos] = esrc[e];
    }
    return;
  }
  mov_tile((movABlocks + mIdx) * 64, sH, x, w1t, w2t, w3t, b1, b2, b3, hout, nrows);
}

// ---------------- scan (merged top+fill): offs + cursor ---------------------
// bsum already holds per-1024-chunk counts (accumulated by hist).
__global__ __launch_bounds__(256)
void scan_fill_kernel(const int* __restrict__ cnt, const int* __restrict__ bsum,
                      int* __restrict__ offs, int* __restrict__ cursor,
                      int nph, int nb) {
  __shared__ int top[256];
  __shared__ int part[256];
  const int b = blockIdx.x, t = threadIdx.x;
  top[t] = (t < nb) ? bsum[t] : 0;
  __syncthreads();
  for (int d = 1; d < 256; d <<= 1) {
    int v = (t >= d) ? top[t - d] : 0;
    __syncthreads();
    top[t] += v;
    __syncthreads();
  }
  const int blockBase = (b == 0) ? 0 : top[b - 1];
  if (b == 0 && t == 0) offs[nph] = top[nb - 1];

  const int base = b * 1024 + t * 4;
  int v[4];
  int s = 0;
#pragma unroll
  for (int i = 0; i < 4; ++i) {
    int idx = base + i;
    v[i] = (idx < nph) ? cnt[idx] : 0;
    s += v[i];
  }
  part[t] = s;
  __syncthreads();
  for (int d = 1; d < 256; d <<= 1) {
    int u = (t >= d) ? part[t - d] : 0;
    __syncthreads();
    part[t] += u;
    __syncthreads();
  }
  int run = blockBase + ((t == 0) ? 0 : part[t - 1]);
#pragma unroll
  for (int i = 0; i < 4; ++i) {
    int idx = base + i;
    if (idx < nph) {
      offs[idx] = run;
      cursor[idx] = run;
      run += v[i];
    }
  }
}

// ---------------- fused gather + phase MLP ----------------------------------
__device__ __forceinline__
void gather_phase(const unsigned short* __restrict__ h, const int* __restrict__ csr,
                  int beg, int end, int l, float out[4]) {
  f32x4 a0 = (f32x4)0.f, a1 = (f32x4)0.f, a2 = (f32x4)0.f, a3 = (f32x4)0.f;
  int j = beg;
  for (; j + 4 <= end; j += 4) {
    int s0 = csr[j], s1 = csr[j + 1], s2 = csr[j + 2], s3 = csr[j + 3];
    ushort4 v0 = *(const ushort4*)(h + (size_t)s0 * 128 + l * 4);
    ushort4 v1 = *(const ushort4*)(h + (size_t)s1 * 128 + l * 4);
    ushort4 v2 = *(const ushort4*)(h + (size_t)s2 * 128 + l * 4);
    ushort4 v3 = *(const ushort4*)(h + (size_t)s3 * 128 + l * 4);
    a0[0] += bf2f(v0.x); a0[1] += bf2f(v0.y); a0[2] += bf2f(v0.z); a0[3] += bf2f(v0.w);
    a1[0] += bf2f(v1.x); a1[1] += bf2f(v1.y); a1[2] += bf2f(v1.z); a1[3] += bf2f(v1.w);
    a2[0] += bf2f(v2.x); a2[1] += bf2f(v2.y); a2[2] += bf2f(v2.z); a2[3] += bf2f(v2.w);
    a3[0] += bf2f(v3.x); a3[1] += bf2f(v3.y); a3[2] += bf2f(v3.z); a3[3] += bf2f(v3.w);
  }
  for (; j < end; ++j) {
    int s = csr[j];
    ushort4 v = *(const ushort4*)(h + (size_t)s * 128 + l * 4);
    a0[0] += bf2f(v.x); a0[1] += bf2f(v.y); a0[2] += bf2f(v.z); a0[3] += bf2f(v.w);
  }
  const float sc = 1.f / (float)max(end - beg, 1);
  out[0] = (a0[0] + a1[0] + a2[0] + a3[0]) * sc;
  out[1] = (a0[1] + a1[1] + a2[1] + a3[1]) * sc;
  out[2] = (a0[2] + a1[2] + a2[2] + a3[2]) * sc;
  out[3] = (a0[3] + a1[3] + a2[3] + a3[3]) * sc;
}

__global__ __launch_bounds__(256)
void phase_fused(const unsigned short* __restrict__ h, const int* __restrict__ csr,
                 const int* __restrict__ offs,
                 const unsigned short* __restrict__ w4t,
                 const unsigned short* __restrict__ w5t,
                 const float* __restrict__ b4, const float* __restrict__ b5,
                 const float* __restrict__ W6, const float* __restrict__ b6,
                 float* __restrict__ logits, int nph) {
  __shared__ unsigned short sH[64 * 128];
  float* sPart = (float*)sH;
  const int tid  = threadIdx.x;
  const int rowBlk = blockIdx.x * 64;

  // ---- stage 1: gather 64 agg rows into sH, 2 phases in flight ----
  {
    const int grp = tid >> 5;
    const int l   = tid & 31;
#pragma unroll 1
    for (int p = 0; p < 8; p += 2) {
      int lrow0 = grp * 8 + p;
      int lrow1 = lrow0 + 1;
      int ph0 = rowBlk + lrow0;
      int ph1 = rowBlk + lrow1;
      float o0[4] = {0.f, 0.f, 0.f, 0.f};
      float o1[4] = {0.f, 0.f, 0.f, 0.f};
      int beg0 = 0, end0 = 0, beg1 = 0, end1 = 0;
      if (ph0 < nph) { beg0 = offs[ph0]; end0 = offs[ph0 + 1]; }
      if (ph1 < nph) { beg1 = offs[ph1]; end1 = offs[ph1 + 1]; }
      gather_phase(h, csr, beg0, end0, l, o0);
      gather_phase(h, csr, beg1, end1, l, o1);
      {
        int gi = l >> 1;
        int slot0 = gi ^ (lrow0 & 7);
        uint2 u0; u0.x = pk2(o0[0], o0[1]); u0.y = pk2(o0[2], o0[3]);
        *(uint2*)&sH[lrow0 * 128 + slot0 * 8 + (l & 1) * 4] = u0;
        int slot1 = gi ^ (lrow1 & 7);
        uint2 u1; u1.x = pk2(o1[0], o1[1]); u1.y = pk2(o1[2], o1[3]);
        *(uint2*)&sH[lrow1 * 128 + slot1 * 8 + (l & 1) * 4] = u1;
      }
    }
  }
  __syncthreads();

  // ---- stage 2: phase MLP ----
  const int lane = tid & 63;
  const int w    = tid >> 6;
  const int rloc = lane & 15;
  const int g    = lane >> 4;
  const int r0w  = (w & 1) * 32;
  const int c0   = (w >> 1) * 64;

  f32x4 acc[2][4];
  short8 Bf[4][4];

#pragma unroll
  for (int ks = 0; ks < 4; ++ks)
#pragma unroll
    for (int cf = 0; cf < 4; ++cf)
      Bf[ks][cf] = *(const short8*)&w4t[(c0 + cf * 16 + rloc) * 128 + ks * 32 + g * 8];
#pragma unroll
  for (int rf = 0; rf < 2; ++rf)
#pragma unroll
    for (int cf = 0; cf < 4; ++cf) acc[rf][cf] = (f32x4)0.f;

#pragma unroll
  for (int ks = 0; ks < 4; ++ks) {
    short8 A0, A1;
    {
      int row = r0w + rloc;
      int slot = (ks * 4 + g) ^ (row & 7);
      A0 = *(const short8*)&sH[row * 128 + slot * 8];
    }
    {
      int row = r0w + 16 + rloc;
      int slot = (ks * 4 + g) ^ (row & 7);
      A1 = *(const short8*)&sH[row * 128 + slot * 8];
    }
#pragma unroll
    for (int cf = 0; cf < 4; ++cf) {
      acc[0][cf] = __builtin_amdgcn_mfma_f32_16x16x32_bf16(A0, Bf[ks][cf], acc[0][cf], 0, 0, 0);
      acc[1][cf] = __builtin_amdgcn_mfma_f32_16x16x32_bf16(A1, Bf[ks][cf], acc[1][cf], 0, 0, 0);
    }
  }
  __syncthreads();

  {
    float bv[4];
#pragma unroll
    for (int cf = 0; cf < 4; ++cf) bv[cf] = b4[c0 + cf * 16 + rloc];
#pragma unroll
    for (int rf = 0; rf < 2; ++rf)
#pragma unroll
      for (int cf = 0; cf < 4; ++cf)
#pragma unroll
        for (int i = 0; i < 4; ++i) {
          int row = r0w + rf * 16 + g * 4 + i;
          int col = c0 + cf * 16 + rloc;
          float v = fmaxf(acc[rf][cf][i] + bv[cf], 0.f);
          sH[row * 128 + (((col >> 3) ^ (row & 7)) << 3) + (col & 7)] = f2bf(v);
        }
  }
  __syncthreads();

#pragma unroll
  for (int ks = 0; ks < 4; ++ks)
#pragma unroll
    for (int cf = 0; cf < 4; ++cf)
      Bf[ks][cf] = *(const short8*)&w5t[(c0 + cf * 16 + rloc) * 128 + ks * 32 + g * 8];
#pragma unroll
  for (int rf = 0; rf < 2; ++rf)
#pragma unroll
    for (int cf = 0; cf < 4; ++cf) acc[rf][cf] = (f32x4)0.f;

#pragma unroll
  for (int ks = 0; ks < 4; ++ks) {
    short8 A0, A1;
    {
      int row = r0w + rloc;
      int slot = (ks * 4 + g) ^ (row & 7);
      A0 = *(const short8*)&sH[row * 128 + slot * 8];
    }
    {
      int row = r0w + 16 + rloc;
      int slot = (ks * 4 + g) ^ (row & 7);
      A1 = *(const short8*)&sH[row * 128 + slot * 8];
    }
#pragma unroll
    for (int cf = 0; cf < 4; ++cf) {
      acc[0][cf] = __builtin_amdgcn_mfma_f32_16x16x32_bf16(A0, Bf[ks][cf], acc[0][cf], 0, 0, 0);
      acc[1][cf] = __builtin_amdgcn_mfma_f32_16x16x32_bf16(A1, Bf[ks][cf], acc[1][cf], 0, 0, 0);
    }
  }

  float part8[2][4];
  {
    float bv[4], wv[4];
#pragma unroll
    for (int cf = 0; cf < 4; ++cf) {
      bv[cf] = b5[c0 + cf * 16 + rloc];
      wv[cf] = W6[c0 + cf * 16 + rloc];
    }
#pragma unroll
    for (int rf = 0; rf < 2; ++rf)
#pragma unroll
      for (int i = 0; i < 4; ++i) {
        float p = 0.f;
#pragma unroll
        for (int cf = 0; cf < 4; ++cf)
          p += fmaxf(acc[rf][cf][i] + bv[cf], 0.f) * wv[cf];
        part8[rf][i] = p;
      }
  }
#pragma unroll
  for (int m = 1; m < 16; m <<= 1) {
#pragma unroll
    for (int rf = 0; rf < 2; ++rf)
#pragma unroll
      for (int i = 0; i < 4; ++i)
        part8[rf][i] += __shfl_xor(part8[rf][i], m, 64);
  }
  __syncthreads();
  if (rloc == 0) {
#pragma unroll
    for (int rf = 0; rf < 2; ++rf)
#pragma unroll
      for (int i = 0; i < 4; ++i)
        sPart[(w >> 1) * 64 + r0w + rf * 16 + g * 4 + i] = part8[rf][i];
  }
  __syncthreads();
  if (tid < 64) {
    int gr = rowBlk + tid;
    if (gr < nph) logits[gr] = sPart[tid] + sPart[64 + tid] + b6[0];
  }
}

// ---------------------------------------------------------------------------
extern "C" void kernel_launch(void* const* d_in, const int* in_sizes, int n_in,
                              void* d_out, int out_size, void* d_ws, size_t ws_size,
                              hipStream_t stream) {
  const float* x  = (const float*)d_in[0];
  const float* W1 = (const float*)d_in[1];
  const float* b1 = (const float*)d_in[2];
  const float* W2 = (const float*)d_in[3];
  const float* b2 = (const float*)d_in[4];
  const float* W3 = (const float*)d_in[5];
  const float* b3 = (const float*)d_in[6];
  const float* W4 = (const float*)d_in[7];
  const float* b4 = (const float*)d_in[8];
  const float* W5 = (const float*)d_in[9];
  const float* b5 = (const float*)d_in[10];
  const float* W6 = (const float*)d_in[11];
  const float* b6 = (const float*)d_in[12];
  const int* esrc = (const int*)d_in[13];
  const int* edst = (const int*)d_in[14];

  const int nmov = in_sizes[0] / 16;
  const int ne   = in_sizes[13];
  const int nph  = out_size;

  char* ws = (char*)d_ws;
  size_t off = 0;
  auto take = [&](size_t bytes) {
    char* p = ws + off;
    off = (off + bytes + 255) & ~(size_t)255;
    return p;
  };
  unsigned short* hbuf = (unsigned short*)take((size_t)nmov * 128 * 2); // 128 MB
  int* csr             = (int*)take((size_t)ne * 4);                   //   4 MB
  int* cnt             = (int*)take((size_t)nph * 4);
  int* offs            = (int*)take(((size_t)nph + 1) * 4);
  int* cursor          = (int*)take((size_t)nph * 4);
  unsigned short* w1t  = (unsigned short*)take(128 * 32 * 2);
  unsigned short* w2t  = (unsigned short*)take(128 * 128 * 2);
  unsigned short* w3t  = (unsigned short*)take(128 * 128 * 2);
  unsigned short* w4t  = (unsigned short*)take(128 * 128 * 2);
  unsigned short* w5t  = (unsigned short*)take(128 * 128 * 2);
  const int nb = (nph + 1023) / 1024;            // <= 256 for nph <= 262144
  int* bsum            = (int*)take((size_t)nb * 4);
  if (off > ws_size) return;

  prep_weights<<<64, 256, 0, stream>>>(W1, W2, W3, W4, W5,
                                       w1t, w2t, w3t, w4t, w5t, cnt, nph, bsum, nb);

  const int movBlocks = (nmov + 63) / 64;
  const int movA = (movBlocks * 9) / 16;
  const int movB = movBlocks - movA;

  const int histB = 256;
  {
    const int N1 = movA + histB;
    int k1 = N1 / histB;
    if (k1 < 2) k1 = 2;
    mov_hist_kernel<<<N1, 256, 0, stream>>>(
        x, w1t, w2t, w3t, b1, b2, b3, hbuf, nmov, edst, cnt, bsum, ne, k1, histB);
  }

  scan_fill_kernel<<<nb, 256, 0, stream>>>(cnt, bsum, offs, cursor, nph, nb);

  const int fillB = 256;
  {
    const int N2 = movB + fillB;
    int k2 = N2 / fillB;
    if (k2 < 2) k2 = 2;
    mov_fill_kernel<<<N2, 256, 0, stream>>>(
        x, w1t, w2t, w3t, b1, b2, b3, hbuf, nmov, movA,
        esrc, edst, cursor, csr, ne, k2, fillB);
  }

  int phBlocks = (nph + 63) / 64;
  phase_fused<<<phBlocks, 256, 0, stream>>>(hbuf, csr, offs, w4t, w5t,
                                            b4, b5, W6, b6, (float*)d_out, nph);
}

// Round 20
// 282.748 us; speedup vs baseline: 3.7842x; 3.7842x over previous
//
#include <hip/hip_runtime.h>
#include <hip/hip_bf16.h>

// ---------------------------------------------------------------------------
// GraphActorNetwork: movement MLP (16->128->128->128) -> scatter-mean over
// edges -> phase MLP (128->128->128->1).
// Round 20 = round 19 resubmitted (round-19 bench died on infra:
// UnresponsiveContainer before any kernel ran).
// Base = r17 (285us). r18's regression (1M atomics on 123 addresses ->
// 1070us) reverted; scan_sum fold redone contention-free: hist role keeps
// an LDS histogram of the 1024-chunk bins (<=123 ints in unused sH) and
// flushes one global atomic per bin per block (63k spread atomics).
// DAG: prep -> [movA||hist+ldsbsum] -> scan_fill -> [movB||fill] -> phase_fused.
// absmax expected unchanged 2.9e-3.
// ---------------------------------------------------------------------------

typedef __attribute__((ext_vector_type(8))) short short8;
typedef __attribute__((ext_vector_type(4))) float f32x4;

union U8 { short8 s8; unsigned int u[4]; };

__device__ __forceinline__ float bf2f(unsigned short u) {
  return __uint_as_float(((unsigned int)u) << 16);
}
__device__ __forceinline__ unsigned short f2bf(float f) {
  unsigned int u = __float_as_uint(f);
  u = (u + 0x7fffu + ((u >> 16) & 1u)) >> 16;   // RNE
  return (unsigned short)u;
}
__device__ __forceinline__ unsigned int pk2(float a, float b) {
  __hip_bfloat162 h = __float22bfloat162_rn(make_float2(a, b));
  unsigned int u;
  __builtin_memcpy(&u, &h, 4);
  return u;
}

// ---------------- prep: bf16 transposed weights + zero cnt/bsum -------------
__global__ __launch_bounds__(256)
void prep_weights(const float* __restrict__ W1, const float* __restrict__ W2,
                  const float* __restrict__ W3, const float* __restrict__ W4,
                  const float* __restrict__ W5,
                  unsigned short* __restrict__ w1t, unsigned short* __restrict__ w2t,
                  unsigned short* __restrict__ w3t, unsigned short* __restrict__ w4t,
                  unsigned short* __restrict__ w5t,
                  int* __restrict__ cnt, int nph, int* __restrict__ bsum, int nb) {
  int t = blockIdx.x * blockDim.x + threadIdx.x;
  int stride = gridDim.x * blockDim.x;
  if (t < 128 * 32) {
    int c = t >> 5, k = t & 31;
    w1t[t] = (k < 16) ? f2bf(W1[k * 128 + c]) : 0;
  }
  for (int i = t; i < 128 * 128; i += stride) {
    int c = i >> 7, k = i & 127;
    w2t[i] = f2bf(W2[k * 128 + c]);
    w3t[i] = f2bf(W3[k * 128 + c]);
    w4t[i] = f2bf(W4[k * 128 + c]);
    w5t[i] = f2bf(W5[k * 128 + c]);
  }
  for (int i = t; i < nph; i += stride) cnt[i] = 0;
  if (t < nb) bsum[t] = 0;
}

// ---------------- mov tile body (r10 proven) --------------------------------
__device__ __forceinline__
void mov_tile(int rowBlk, unsigned short* sH,
              const float* __restrict__ x,
              const unsigned short* __restrict__ w1t,
              const unsigned short* __restrict__ w2t,
              const unsigned short* __restrict__ w3t,
              const float* __restrict__ b1, const float* __restrict__ b2,
              const float* __restrict__ b3,
              unsigned short* __restrict__ hout, int nrows) {
  const int tid  = threadIdx.x;
  const int lane = tid & 63;
  const int w    = tid >> 6;
  const int li   = lane & 15;
  const int g    = lane >> 4;
  const int r0w  = (w & 1) * 32;
  const int c0   = (w >> 1) * 64;

  f32x4 acc[2][4];
  short8 Bf[4][4];

#pragma unroll
  for (int cf = 0; cf < 4; ++cf) {
    float4 b4 = *(const float4*)&b1[c0 + cf * 16 + g * 4];
#pragma unroll
    for (int rf = 0; rf < 2; ++rf) {
      acc[rf][cf][0] = b4.x; acc[rf][cf][1] = b4.y;
      acc[rf][cf][2] = b4.z; acc[rf][cf][3] = b4.w;
    }
  }
  {
    short8 Ax[2];
#pragma unroll
    for (int rf = 0; rf < 2; ++rf) {
      U8 a; a.s8 = (short8)0;
      int row = rowBlk + r0w + rf * 16 + li;
      if (g < 2 && row < nrows) {
        const float* xp = x + (size_t)row * 16 + g * 8;
        float4 u0 = *(const float4*)xp;
        float4 u1 = *(const float4*)(xp + 4);
        a.u[0] = pk2(u0.x, u0.y); a.u[1] = pk2(u0.z, u0.w);
        a.u[2] = pk2(u1.x, u1.y); a.u[3] = pk2(u1.z, u1.w);
      }
      Ax[rf] = a.s8;
    }
    short8 B1[4];
#pragma unroll
    for (int cf = 0; cf < 4; ++cf)
      B1[cf] = *(const short8*)&w1t[(c0 + cf * 16 + li) * 32 + g * 8];
#pragma unroll
    for (int rf = 0; rf < 2; ++rf)
#pragma unroll
      for (int cf = 0; cf < 4; ++cf)
        acc[rf][cf] = __builtin_amdgcn_mfma_f32_16x16x32_bf16(B1[cf], Ax[rf], acc[rf][cf], 0, 0, 0);
  }

#pragma unroll
  for (int rf = 0; rf < 2; ++rf) {
    int s = r0w + rf * 16 + li;
    unsigned short* dst = &sH[s * 128 + (g & 1) * 4];
    int sx = s & 7;
#pragma unroll
    for (int cf = 0; cf < 4; ++cf) {
      int gi = (c0 >> 3) + cf * 2 + (g >> 1);
      int slot = gi ^ sx;
      uint2 u;
      u.x = pk2(fmaxf(acc[rf][cf][0], 0.f), fmaxf(acc[rf][cf][1], 0.f));
      u.y = pk2(fmaxf(acc[rf][cf][2], 0.f), fmaxf(acc[rf][cf][3], 0.f));
      *(uint2*)(dst + slot * 8) = u;
    }
  }
  __syncthreads();

  const unsigned short* wts[2] = { w2t, w3t };
  const float* bs[2] = { b2, b3 };
#pragma unroll 1
  for (int layer = 0; layer < 2; ++layer) {
    const unsigned short* wt = wts[layer];
    const float* bb = bs[layer];
#pragma unroll
    for (int ks = 0; ks < 4; ++ks)
#pragma unroll
      for (int cf = 0; cf < 4; ++cf)
        Bf[ks][cf] = *(const short8*)&wt[(c0 + cf * 16 + li) * 128 + ks * 32 + g * 8];

#pragma unroll
    for (int cf = 0; cf < 4; ++cf) {
      float4 b4 = *(const float4*)&bb[c0 + cf * 16 + g * 4];
#pragma unroll
      for (int rf = 0; rf < 2; ++rf) {
        acc[rf][cf][0] = b4.x; acc[rf][cf][1] = b4.y;
        acc[rf][cf][2] = b4.z; acc[rf][cf][3] = b4.w;
      }
    }

#pragma unroll
    for (int ks = 0; ks < 4; ++ks) {
      short8 Ar[2];
#pragma unroll
      for (int rf = 0; rf < 2; ++rf) {
        int s = r0w + rf * 16 + li;
        int slot = (ks * 4 + g) ^ (s & 7);
        Ar[rf] = *(const short8*)&sH[s * 128 + slot * 8];
      }
#pragma unroll
      for (int rf = 0; rf < 2; ++rf)
#pragma unroll
        for (int cf = 0; cf < 4; ++cf)
          acc[rf][cf] = __builtin_amdgcn_mfma_f32_16x16x32_bf16(Bf[ks][cf], Ar[rf], acc[rf][cf], 0, 0, 0);
    }
    __syncthreads();

#pragma unroll
    for (int rf = 0; rf < 2; ++rf) {
      int s = r0w + rf * 16 + li;
      unsigned short* dst = &sH[s * 128 + (g & 1) * 4];
      int sx = s & 7;
#pragma unroll
      for (int cf = 0; cf < 4; ++cf) {
        int gi = (c0 >> 3) + cf * 2 + (g >> 1);
        int slot = gi ^ sx;
        uint2 u;
        u.x = pk2(fmaxf(acc[rf][cf][0], 0.f), fmaxf(acc[rf][cf][1], 0.f));
        u.y = pk2(fmaxf(acc[rf][cf][2], 0.f), fmaxf(acc[rf][cf][3], 0.f));
        *(uint2*)(dst + slot * 8) = u;
      }
    }
    __syncthreads();
  }

  {
    int r = tid >> 2;
    int q = tid & 3;
    int grow = rowBlk + r;
    if (grow < nrows) {
#pragma unroll
      for (int i = 0; i < 4; ++i) {
        int gi = q * 4 + i;
        int slot = gi ^ (r & 7);
        short8 v = *(const short8*)&sH[r * 128 + slot * 8];
        *(short8*)(hout + (size_t)grow * 128 + gi * 8) = v;
      }
    }
  }
}

// role map: every k-th block (b%k==k-1, b/k<otherB) takes the "other" role.
__device__ __forceinline__ bool role_other(int b, int k, int otherB, int* oIdx, int* mIdx) {
  bool other = ((b % k) == (k - 1)) && ((b / k) < otherB);
  *oIdx = b / k;
  int before = min((b + 1) / k, otherB);
  *mIdx = b - before;
  return other;
}

// ---------------- K1: movA interleaved with hist (+LDS bsum histogram) ------
__global__ __launch_bounds__(256)
void mov_hist_kernel(const float* __restrict__ x,
                     const unsigned short* __restrict__ w1t,
                     const unsigned short* __restrict__ w2t,
                     const unsigned short* __restrict__ w3t,
                     const float* __restrict__ b1, const float* __restrict__ b2,
                     const float* __restrict__ b3,
                     unsigned short* __restrict__ hout, int nrows,
                     const int* __restrict__ edst, int* __restrict__ cnt,
                     int* __restrict__ bsum, int nb, int ne, int k, int histB) {
  __shared__ unsigned short sH[64 * 128];
  int oIdx, mIdx;
  if (role_other(blockIdx.x, k, histB, &oIdx, &mIdx)) {
    // hist role: global cnt atomics (125k addresses, fine) + LDS histogram
    // of the 1024-chunk bins (<=123 bins), flushed once per block.
    int* lbs = (int*)sH;
    for (int i = threadIdx.x; i < nb; i += 256) lbs[i] = 0;
    __syncthreads();
    int i = oIdx * 256 + threadIdx.x;
    int stride = histB * 256;
    for (int e = i; e < ne; e += stride) {
      int d = edst[e];
      atomicAdd(cnt + d, 1);
      atomicAdd(&lbs[d >> 10], 1);
    }
    __syncthreads();
    for (int j = threadIdx.x; j < nb; j += 256) {
      int v = lbs[j];
      if (v) atomicAdd(bsum + j, v);
    }
    return;
  }
  mov_tile(mIdx * 64, sH, x, w1t, w2t, w3t, b1, b2, b3, hout, nrows);
}

// ---------------- K2: movB interleaved with fill ----------------------------
__global__ __launch_bounds__(256)
void mov_fill_kernel(const float* __restrict__ x,
                     const unsigned short* __restrict__ w1t,
                     const unsigned short* __restrict__ w2t,
                     const unsigned short* __restrict__ w3t,
                     const float* __restrict__ b1, const float* __restrict__ b2,
                     const float* __restrict__ b3,
                     unsigned short* __restrict__ hout, int nrows, int movABlocks,
                     const int* __restrict__ esrc, const int* __restrict__ edst,
                     int* __restrict__ cursor, int* __restrict__ csr, int ne,
                     int k, int fillB) {
  __shared__ unsigned short sH[64 * 128];
  int oIdx, mIdx;
  if (role_other(blockIdx.x, k, fillB, &oIdx, &mIdx)) {
    int i = oIdx * 256 + threadIdx.x;
    int stride = fillB * 256;
    for (int e = i; e < ne; e += stride) {
      int d = edst[e];
      int pos = atomicAdd(cursor + d, 1);
      csr[pos] = esrc[e];
    }
    return;
  }
  mov_tile((movABlocks + mIdx) * 64, sH, x, w1t, w2t, w3t, b1, b2, b3, hout, nrows);
}

// ---------------- scan (merged top+fill): offs + cursor ---------------------
__global__ __launch_bounds__(256)
void scan_fill_kernel(const int* __restrict__ cnt, const int* __restrict__ bsum,
                      int* __restrict__ offs, int* __restrict__ cursor,
                      int nph, int nb) {
  __shared__ int top[256];
  __shared__ int part[256];
  const int b = blockIdx.x, t = threadIdx.x;
  top[t] = (t < nb) ? bsum[t] : 0;
  __syncthreads();
  for (int d = 1; d < 256; d <<= 1) {
    int v = (t >= d) ? top[t - d] : 0;
    __syncthreads();
    top[t] += v;
    __syncthreads();
  }
  const int blockBase = (b == 0) ? 0 : top[b - 1];
  if (b == 0 && t == 0) offs[nph] = top[nb - 1];

  const int base = b * 1024 + t * 4;
  int v[4];
  int s = 0;
#pragma unroll
  for (int i = 0; i < 4; ++i) {
    int idx = base + i;
    v[i] = (idx < nph) ? cnt[idx] : 0;
    s += v[i];
  }
  part[t] = s;
  __syncthreads();
  for (int d = 1; d < 256; d <<= 1) {
    int u = (t >= d) ? part[t - d] : 0;
    __syncthreads();
    part[t] += u;
    __syncthreads();
  }
  int run = blockBase + ((t == 0) ? 0 : part[t - 1]);
#pragma unroll
  for (int i = 0; i < 4; ++i) {
    int idx = base + i;
    if (idx < nph) {
      offs[idx] = run;
      cursor[idx] = run;
      run += v[i];
    }
  }
}

// ---------------- fused gather + phase MLP ----------------------------------
__device__ __forceinline__
void gather_phase(const unsigned short* __restrict__ h, const int* __restrict__ csr,
                  int beg, int end, int l, float out[4]) {
  f32x4 a0 = (f32x4)0.f, a1 = (f32x4)0.f, a2 = (f32x4)0.f, a3 = (f32x4)0.f;
  int j = beg;
  for (; j + 4 <= end; j += 4) {
    int s0 = csr[j], s1 = csr[j + 1], s2 = csr[j + 2], s3 = csr[j + 3];
    ushort4 v0 = *(const ushort4*)(h + (size_t)s0 * 128 + l * 4);
    ushort4 v1 = *(const ushort4*)(h + (size_t)s1 * 128 + l * 4);
    ushort4 v2 = *(const ushort4*)(h + (size_t)s2 * 128 + l * 4);
    ushort4 v3 = *(const ushort4*)(h + (size_t)s3 * 128 + l * 4);
    a0[0] += bf2f(v0.x); a0[1] += bf2f(v0.y); a0[2] += bf2f(v0.z); a0[3] += bf2f(v0.w);
    a1[0] += bf2f(v1.x); a1[1] += bf2f(v1.y); a1[2] += bf2f(v1.z); a1[3] += bf2f(v1.w);
    a2[0] += bf2f(v2.x); a2[1] += bf2f(v2.y); a2[2] += bf2f(v2.z); a2[3] += bf2f(v2.w);
    a3[0] += bf2f(v3.x); a3[1] += bf2f(v3.y); a3[2] += bf2f(v3.z); a3[3] += bf2f(v3.w);
  }
  for (; j < end; ++j) {
    int s = csr[j];
    ushort4 v = *(const ushort4*)(h + (size_t)s * 128 + l * 4);
    a0[0] += bf2f(v.x); a0[1] += bf2f(v.y); a0[2] += bf2f(v.z); a0[3] += bf2f(v.w);
  }
  const float sc = 1.f / (float)max(end - beg, 1);
  out[0] = (a0[0] + a1[0] + a2[0] + a3[0]) * sc;
  out[1] = (a0[1] + a1[1] + a2[1] + a3[1]) * sc;
  out[2] = (a0[2] + a1[2] + a2[2] + a3[2]) * sc;
  out[3] = (a0[3] + a1[3] + a2[3] + a3[3]) * sc;
}

__global__ __launch_bounds__(256)
void phase_fused(const unsigned short* __restrict__ h, const int* __restrict__ csr,
                 const int* __restrict__ offs,
                 const unsigned short* __restrict__ w4t,
                 const unsigned short* __restrict__ w5t,
                 const float* __restrict__ b4, const float* __restrict__ b5,
                 const float* __restrict__ W6, const float* __restrict__ b6,
                 float* __restrict__ logits, int nph) {
  __shared__ unsigned short sH[64 * 128];
  float* sPart = (float*)sH;
  const int tid  = threadIdx.x;
  const int rowBlk = blockIdx.x * 64;

  {
    const int grp = tid >> 5;
    const int l   = tid & 31;
#pragma unroll 1
    for (int p = 0; p < 8; p += 2) {
      int lrow0 = grp * 8 + p;
      int lrow1 = lrow0 + 1;
      int ph0 = rowBlk + lrow0;
      int ph1 = rowBlk + lrow1;
      float o0[4] = {0.f, 0.f, 0.f, 0.f};
      float o1[4] = {0.f, 0.f, 0.f, 0.f};
      int beg0 = 0, end0 = 0, beg1 = 0, end1 = 0;
      if (ph0 < nph) { beg0 = offs[ph0]; end0 = offs[ph0 + 1]; }
      if (ph1 < nph) { beg1 = offs[ph1]; end1 = offs[ph1 + 1]; }
      gather_phase(h, csr, beg0, end0, l, o0);
      gather_phase(h, csr, beg1, end1, l, o1);
      {
        int gi = l >> 1;
        int slot0 = gi ^ (lrow0 & 7);
        uint2 u0; u0.x = pk2(o0[0], o0[1]); u0.y = pk2(o0[2], o0[3]);
        *(uint2*)&sH[lrow0 * 128 + slot0 * 8 + (l & 1) * 4] = u0;
        int slot1 = gi ^ (lrow1 & 7);
        uint2 u1; u1.x = pk2(o1[0], o1[1]); u1.y = pk2(o1[2], o1[3]);
        *(uint2*)&sH[lrow1 * 128 + slot1 * 8 + (l & 1) * 4] = u1;
      }
    }
  }
  __syncthreads();

  const int lane = tid & 63;
  const int w    = tid >> 6;
  const int rloc = lane & 15;
  const int g    = lane >> 4;
  const int r0w  = (w & 1) * 32;
  const int c0   = (w >> 1) * 64;

  f32x4 acc[2][4];
  short8 Bf[4][4];

#pragma unroll
  for (int ks = 0; ks < 4; ++ks)
#pragma unroll
    for (int cf = 0; cf < 4; ++cf)
      Bf[ks][cf] = *(const short8*)&w4t[(c0 + cf * 16 + rloc) * 128 + ks * 32 + g * 8];
#pragma unroll
  for (int rf = 0; rf < 2; ++rf)
#pragma unroll
    for (int cf = 0; cf < 4; ++cf) acc[rf][cf] = (f32x4)0.f;

#pragma unroll
  for (int ks = 0; ks < 4; ++ks) {
    short8 A0, A1;
    {
      int row = r0w + rloc;
      int slot = (ks * 4 + g) ^ (row & 7);
      A0 = *(const short8*)&sH[row * 128 + slot * 8];
    }
    {
      int row = r0w + 16 + rloc;
      int slot = (ks * 4 + g) ^ (row & 7);
      A1 = *(const short8*)&sH[row * 128 + slot * 8];
    }
#pragma unroll
    for (int cf = 0; cf < 4; ++cf) {
      acc[0][cf] = __builtin_amdgcn_mfma_f32_16x16x32_bf16(A0, Bf[ks][cf], acc[0][cf], 0, 0, 0);
      acc[1][cf] = __builtin_amdgcn_mfma_f32_16x16x32_bf16(A1, Bf[ks][cf], acc[1][cf], 0, 0, 0);
    }
  }
  __syncthreads();

  {
    float bv[4];
#pragma unroll
    for (int cf = 0; cf < 4; ++cf) bv[cf] = b4[c0 + cf * 16 + rloc];
#pragma unroll
    for (int rf = 0; rf < 2; ++rf)
#pragma unroll
      for (int cf = 0; cf < 4; ++cf)
#pragma unroll
        for (int i = 0; i < 4; ++i) {
          int row = r0w + rf * 16 + g * 4 + i;
          int col = c0 + cf * 16 + rloc;
          float v = fmaxf(acc[rf][cf][i] + bv[cf], 0.f);
          sH[row * 128 + (((col >> 3) ^ (row & 7)) << 3) + (col & 7)] = f2bf(v);
        }
  }
  __syncthreads();

#pragma unroll
  for (int ks = 0; ks < 4; ++ks)
#pragma unroll
    for (int cf = 0; cf < 4; ++cf)
      Bf[ks][cf] = *(const short8*)&w5t[(c0 + cf * 16 + rloc) * 128 + ks * 32 + g * 8];
#pragma unroll
  for (int rf = 0; rf < 2; ++rf)
#pragma unroll
    for (int cf = 0; cf < 4; ++cf) acc[rf][cf] = (f32x4)0.f;

#pragma unroll
  for (int ks = 0; ks < 4; ++ks) {
    short8 A0, A1;
    {
      int row = r0w + rloc;
      int slot = (ks * 4 + g) ^ (row & 7);
      A0 = *(const short8*)&sH[row * 128 + slot * 8];
    }
    {
      int row = r0w + 16 + rloc;
      int slot = (ks * 4 + g) ^ (row & 7);
      A1 = *(const short8*)&sH[row * 128 + slot * 8];
    }
#pragma unroll
    for (int cf = 0; cf < 4; ++cf) {
      acc[0][cf] = __builtin_amdgcn_mfma_f32_16x16x32_bf16(A0, Bf[ks][cf], acc[0][cf], 0, 0, 0);
      acc[1][cf] = __builtin_amdgcn_mfma_f32_16x16x32_bf16(A1, Bf[ks][cf], acc[1][cf], 0, 0, 0);
    }
  }

  float part8[2][4];
  {
    float bv[4], wv[4];
#pragma unroll
    for (int cf = 0; cf < 4; ++cf) {
      bv[cf] = b5[c0 + cf * 16 + rloc];
      wv[cf] = W6[c0 + cf * 16 + rloc];
    }
#pragma unroll
    for (int rf = 0; rf < 2; ++rf)
#pragma unroll
      for (int i = 0; i < 4; ++i) {
        float p = 0.f;
#pragma unroll
        for (int cf = 0; cf < 4; ++cf)
          p += fmaxf(acc[rf][cf][i] + bv[cf], 0.f) * wv[cf];
        part8[rf][i] = p;
      }
  }
#pragma unroll
  for (int m = 1; m < 16; m <<= 1) {
#pragma unroll
    for (int rf = 0; rf < 2; ++rf)
#pragma unroll
      for (int i = 0; i < 4; ++i)
        part8[rf][i] += __shfl_xor(part8[rf][i], m, 64);
  }
  __syncthreads();
  if (rloc == 0) {
#pragma unroll
    for (int rf = 0; rf < 2; ++rf)
#pragma unroll
      for (int i = 0; i < 4; ++i)
        sPart[(w >> 1) * 64 + r0w + rf * 16 + g * 4 + i] = part8[rf][i];
  }
  __syncthreads();
  if (tid < 64) {
    int gr = rowBlk + tid;
    if (gr < nph) logits[gr] = sPart[tid] + sPart[64 + tid] + b6[0];
  }
}

// ---------------------------------------------------------------------------
extern "C" void kernel_launch(void* const* d_in, const int* in_sizes, int n_in,
                              void* d_out, int out_size, void* d_ws, size_t ws_size,
                              hipStream_t stream) {
  const float* x  = (const float*)d_in[0];
  const float* W1 = (const float*)d_in[1];
  const float* b1 = (const float*)d_in[2];
  const float* W2 = (const float*)d_in[3];
  const float* b2 = (const float*)d_in[4];
  const float* W3 = (const float*)d_in[5];
  const float* b3 = (const float*)d_in[6];
  const float* W4 = (const float*)d_in[7];
  const float* b4 = (const float*)d_in[8];
  const float* W5 = (const float*)d_in[9];
  const float* b5 = (const float*)d_in[10];
  const float* W6 = (const float*)d_in[11];
  const float* b6 = (const float*)d_in[12];
  const int* esrc = (const int*)d_in[13];
  const int* edst = (const int*)d_in[14];

  const int nmov = in_sizes[0] / 16;
  const int ne   = in_sizes[13];
  const int nph  = out_size;

  char* ws = (char*)d_ws;
  size_t off = 0;
  auto take = [&](size_t bytes) {
    char* p = ws + off;
    off = (off + bytes + 255) & ~(size_t)255;
    return p;
  };
  unsigned short* hbuf = (unsigned short*)take((size_t)nmov * 128 * 2); // 128 MB
  int* csr             = (int*)take((size_t)ne * 4);                   //   4 MB
  int* cnt             = (int*)take((size_t)nph * 4);
  int* offs            = (int*)take(((size_t)nph + 1) * 4);
  int* cursor          = (int*)take((size_t)nph * 4);
  unsigned short* w1t  = (unsigned short*)take(128 * 32 * 2);
  unsigned short* w2t  = (unsigned short*)take(128 * 128 * 2);
  unsigned short* w3t  = (unsigned short*)take(128 * 128 * 2);
  unsigned short* w4t  = (unsigned short*)take(128 * 128 * 2);
  unsigned short* w5t  = (unsigned short*)take(128 * 128 * 2);
  const int nb = (nph + 1023) / 1024;            // <= 256 for nph <= 262144
  int* bsum            = (int*)take((size_t)nb * 4);
  if (off > ws_size) return;

  prep_weights<<<64, 256, 0, stream>>>(W1, W2, W3, W4, W5,
                                       w1t, w2t, w3t, w4t, w5t, cnt, nph, bsum, nb);

  const int movBlocks = (nmov + 63) / 64;
  const int movA = (movBlocks * 9) / 16;
  const int movB = movBlocks - movA;

  const int histB = 512;
  {
    const int N1 = movA + histB;
    int k1 = N1 / histB;
    if (k1 < 2) k1 = 2;
    mov_hist_kernel<<<N1, 256, 0, stream>>>(
        x, w1t, w2t, w3t, b1, b2, b3, hbuf, nmov, edst, cnt, bsum, nb, ne, k1, histB);
  }

  scan_fill_kernel<<<nb, 256, 0, stream>>>(cnt, bsum, offs, cursor, nph, nb);

  const int fillB = 512;
  {
    const int N2 = movB + fillB;
    int k2 = N2 / fillB;
    if (k2 < 2) k2 = 2;
    mov_fill_kernel<<<N2, 256, 0, stream>>>(
        x, w1t, w2t, w3t, b1, b2, b3, hbuf, nmov, movA,
        esrc, edst, cursor, csr, ne, k2, fillB);
  }

  int phBlocks = (nph + 63) / 64;
  phase_fused<<<phBlocks, 256, 0, stream>>>(hbuf, csr, offs, w4t, w5t,
                                            b4, b5, W6, b6, (float*)d_out, nph);
}